// Round 1
// baseline (544.811 us; speedup 1.0000x reference)
//
#include <hip/hip_runtime.h>

#define N_NODES 8192
#define IN_DIM  512
#define HID     256
#define LAT     128
#define NEDGE   262144

typedef __attribute__((ext_vector_type(8))) short  bf16x8;
typedef __attribute__((ext_vector_type(4))) float  f32x4;
typedef unsigned short u16;
typedef __attribute__((ext_vector_type(4))) unsigned short u16x4;

// ---- bf16 helpers (manual, RNE) ----
static __device__ inline u16 f2bf(float f) {
    unsigned u = __float_as_uint(f);
    unsigned r = (u + 0x7fffu + ((u >> 16) & 1u)) >> 16;
    return (u16)r;
}
static __device__ inline float bf2f(u16 s) {
    return __uint_as_float(((unsigned)s) << 16);
}

// ================= CSR build =================

__global__ __launch_bounds__(256) void count_kernel(const int* __restrict__ dst,
                                                    int* __restrict__ cnt) {
    int e = blockIdx.x * 256 + threadIdx.x;
    atomicAdd(&cnt[dst[e]], 1);
}

__global__ __launch_bounds__(256) void dinv_kernel(const int* __restrict__ cnt,
                                                   float* __restrict__ dinv) {
    int v = blockIdx.x * 256 + threadIdx.x;
    dinv[v] = rsqrtf((float)cnt[v] + 1.0f);   // +1 self-loop
}

// single-block exclusive scan of 8192 counts -> rowptr[8193], cursor copy
__global__ __launch_bounds__(256) void scan_kernel(const int* __restrict__ cnt,
                                                   int* __restrict__ rowptr,
                                                   int* __restrict__ cursor) {
    __shared__ int part[256];
    const int t = threadIdx.x;
    const int base = t * 32;
    int local[32];
    int s = 0;
#pragma unroll
    for (int i = 0; i < 32; ++i) { local[i] = s; s += cnt[base + i]; }
    part[t] = s;
    __syncthreads();
    for (int off = 1; off < 256; off <<= 1) {
        int v = 0;
        if (t >= off) v = part[t - off];
        __syncthreads();
        if (t >= off) part[t] += v;
        __syncthreads();
    }
    int pre = (t == 0) ? 0 : part[t - 1];
#pragma unroll
    for (int i = 0; i < 32; ++i) {
        int r = pre + local[i];
        rowptr[base + i] = r;
        cursor[base + i] = r;
    }
    if (t == 255) rowptr[8192] = part[255];
}

__global__ __launch_bounds__(256) void fill_kernel(const int* __restrict__ src,
                                                   const int* __restrict__ dst,
                                                   int* __restrict__ cursor,
                                                   int* __restrict__ ebuf) {
    int e = blockIdx.x * 256 + threadIdx.x;
    int pos = atomicAdd(&cursor[dst[e]], 1);
    ebuf[pos] = src[e];
}

// ================= split-bf16 conversion =================

// x [N,512] f32 -> xhi/xlo bf16, 4 elems/thread
__global__ __launch_bounds__(256) void convx_kernel(const float* __restrict__ X,
                                                    u16* __restrict__ xh,
                                                    u16* __restrict__ xl) {
    int t = blockIdx.x * 256 + threadIdx.x;
    f32x4 v = *(const f32x4*)(X + (size_t)t * 4);
    u16x4 h, l;
#pragma unroll
    for (int j = 0; j < 4; ++j) {
        h[j] = f2bf(v[j]);
        l[j] = f2bf(v[j] - bf2f(h[j]));
    }
    *(u16x4*)(xh + (size_t)t * 4) = h;
    *(u16x4*)(xl + (size_t)t * 4) = l;
}

// W [K,N] f32 -> Wt hi/lo [roff+N, Kld] bf16 (transposed), 1 elem/thread
__global__ __launch_bounds__(256) void convw_kernel(const float* __restrict__ W,
                                                    u16* __restrict__ th,
                                                    u16* __restrict__ tl,
                                                    int K, int N, int Kld, int roff) {
    int e = blockIdx.x * 256 + threadIdx.x;
    if (e >= K * N) return;
    int k = e / N, n = e - k * N;
    float f = W[e];
    u16 hi = f2bf(f);
    u16 lo = f2bf(f - bf2f(hi));
    size_t o = (size_t)(roff + n) * Kld + k;
    th[o] = hi;
    tl[o] = lo;
}

// ================= split-bf16 MFMA GEMM =================
// C[M,ldc] = (Ah+Al)[M,K] @ (Bth+Btl)^T  where Bt rows are B columns.
// Block = 4 waves (2x2), each wave a 64x64 tile -> 128x128 per block.
// 3-pass split: hi*hi + hi*lo + lo*hi (lo*lo ~ 2^-16, dropped).
__global__ __launch_bounds__(256) void gemm_mfma(const u16* __restrict__ Ah,
                                                 const u16* __restrict__ Al,
                                                 const u16* __restrict__ Bth,
                                                 const u16* __restrict__ Btl,
                                                 float* __restrict__ C,
                                                 int K, int ldc) {
    const int lane = threadIdx.x & 63;
    const int wave = threadIdx.x >> 6;
    const int l16 = lane & 15, quad = lane >> 4;
    const int rowBase = blockIdx.y * 128 + (wave >> 1) * 64;
    const int colBase = blockIdx.x * 128 + (wave & 1) * 64;

    f32x4 acc[4][4] = {};

    for (int k0 = 0; k0 < K; k0 += 32) {
        const int kk = k0 + quad * 8;
        bf16x8 ah[4], al[4], bh[4], bl[4];
#pragma unroll
        for (int r = 0; r < 4; ++r) {
            int row = rowBase + r * 16 + l16;
            ah[r] = *(const bf16x8*)(Ah + (size_t)row * K + kk);
            al[r] = *(const bf16x8*)(Al + (size_t)row * K + kk);
        }
#pragma unroll
        for (int c = 0; c < 4; ++c) {
            int row = colBase + c * 16 + l16;
            bh[c] = *(const bf16x8*)(Bth + (size_t)row * K + kk);
            bl[c] = *(const bf16x8*)(Btl + (size_t)row * K + kk);
        }
#pragma unroll
        for (int r = 0; r < 4; ++r)
#pragma unroll
            for (int c = 0; c < 4; ++c) {
                acc[r][c] = __builtin_amdgcn_mfma_f32_16x16x32_bf16(ah[r], bh[c], acc[r][c], 0, 0, 0);
                acc[r][c] = __builtin_amdgcn_mfma_f32_16x16x32_bf16(ah[r], bl[c], acc[r][c], 0, 0, 0);
                acc[r][c] = __builtin_amdgcn_mfma_f32_16x16x32_bf16(al[r], bh[c], acc[r][c], 0, 0, 0);
            }
    }

#pragma unroll
    for (int r = 0; r < 4; ++r)
#pragma unroll
        for (int c = 0; c < 4; ++c)
#pragma unroll
            for (int i = 0; i < 4; ++i) {
                int orow = rowBase + r * 16 + quad * 4 + i;
                int ocol = colBase + c * 16 + l16;
                C[(size_t)orow * ldc + ocol] = acc[r][c][i];
            }
}

// ================= CSR gather aggregation =================
// conv1: h1[v] = relu( sum_s nrm*pre1[s] + d2*pre1[v] + b1 ), one wave per node
// output split-bf16 (feeds MFMA gemm2)
__global__ __launch_bounds__(256) void gather1_kernel(const float* __restrict__ pre1,
                                                      u16* __restrict__ h1h,
                                                      u16* __restrict__ h1l,
                                                      const int* __restrict__ rowptr,
                                                      const int* __restrict__ ebuf,
                                                      const float* __restrict__ dinv,
                                                      const float* __restrict__ b1) {
    const int wave = threadIdx.x >> 6, lane = threadIdx.x & 63;
    const int v = blockIdx.x * 4 + wave;
    const int c = lane * 4;
    const float dv = dinv[v];
    f32x4 acc = *(const f32x4*)(pre1 + (size_t)v * HID + c);
    acc *= dv * dv;
    int i = rowptr[v], end = rowptr[v + 1];
    for (; i + 1 < end; i += 2) {
        int s0 = ebuf[i], s1 = ebuf[i + 1];
        float n0 = dv * dinv[s0], n1 = dv * dinv[s1];
        f32x4 h0 = *(const f32x4*)(pre1 + (size_t)s0 * HID + c);
        f32x4 h1v = *(const f32x4*)(pre1 + (size_t)s1 * HID + c);
#pragma unroll
        for (int j = 0; j < 4; ++j) acc[j] += n0 * h0[j] + n1 * h1v[j];
    }
    if (i < end) {
        int s0 = ebuf[i];
        float n0 = dv * dinv[s0];
        f32x4 h0 = *(const f32x4*)(pre1 + (size_t)s0 * HID + c);
#pragma unroll
        for (int j = 0; j < 4; ++j) acc[j] += n0 * h0[j];
    }
    f32x4 bb = *(const f32x4*)(b1 + c);
    u16x4 hv, lv;
#pragma unroll
    for (int j = 0; j < 4; ++j) {
        float h = fmaxf(acc[j] + bb[j], 0.0f);
        hv[j] = f2bf(h);
        lv[j] = f2bf(h - bf2f(hv[j]));
    }
    *(u16x4*)(h1h + (size_t)v * HID + c) = hv;
    *(u16x4*)(h1l + (size_t)v * HID + c) = lv;
}

// conv2 + reparametrize: pre2 cols 0..127 = mu-pre, 128..255 = ls-pre.
__global__ __launch_bounds__(256) void gather2_kernel(const float* __restrict__ pre2,
                                                      const int* __restrict__ rowptr,
                                                      const int* __restrict__ ebuf,
                                                      const float* __restrict__ dinv,
                                                      const float* __restrict__ bmu,
                                                      const float* __restrict__ bls,
                                                      const float* __restrict__ eps,
                                                      float* __restrict__ out_mu,
                                                      float* __restrict__ out_ls,
                                                      u16* __restrict__ zhi,
                                                      u16* __restrict__ zlo) {
    const int wave = threadIdx.x >> 6, lane = threadIdx.x & 63;
    const int v = blockIdx.x * 4 + wave;
    const int c = lane * 4;
    const float dv = dinv[v];
    f32x4 acc = *(const f32x4*)(pre2 + (size_t)v * HID + c);
    acc *= dv * dv;
    int i = rowptr[v], end = rowptr[v + 1];
    for (; i + 1 < end; i += 2) {
        int s0 = ebuf[i], s1 = ebuf[i + 1];
        float n0 = dv * dinv[s0], n1 = dv * dinv[s1];
        f32x4 h0 = *(const f32x4*)(pre2 + (size_t)s0 * HID + c);
        f32x4 h1v = *(const f32x4*)(pre2 + (size_t)s1 * HID + c);
#pragma unroll
        for (int j = 0; j < 4; ++j) acc[j] += n0 * h0[j] + n1 * h1v[j];
    }
    if (i < end) {
        int s0 = ebuf[i];
        float n0 = dv * dinv[s0];
        f32x4 h0 = *(const f32x4*)(pre2 + (size_t)s0 * HID + c);
#pragma unroll
        for (int j = 0; j < 4; ++j) acc[j] += n0 * h0[j];
    }
    // bias
    const float* bias = (lane < 32) ? (bmu + c) : (bls + (c - 128));
    f32x4 bb = *(const f32x4*)bias;
#pragma unroll
    for (int j = 0; j < 4; ++j) acc[j] += bb[j];

    // pair mu (lane<32) with ls (lane+32)
    f32x4 other;
#pragma unroll
    for (int j = 0; j < 4; ++j) other[j] = __shfl(acc[j], (lane + 32) & 63, 64);

    if (lane < 32) {
        int idx = v * LAT + c;
        f32x4 ep = *(const f32x4*)(eps + idx);
        *(f32x4*)(out_mu + idx) = acc;
#pragma unroll
        for (int j = 0; j < 4; ++j) {
            float z = ep[j] * __expf(other[j]) + acc[j];
            u16 hi = f2bf(z);
            zhi[idx + j] = hi;
            zlo[idx + j] = f2bf(z - bf2f(hi));
        }
    } else {
        int idx = v * LAT + (c - 128);
        *(f32x4*)(out_ls + idx) = acc;
    }
}

// ================= adj = sigmoid(z z^T), split-bf16 MFMA =================
__global__ __launch_bounds__(256) void zzt_kernel(const u16* __restrict__ zhi,
                                                  const u16* __restrict__ zlo,
                                                  float* __restrict__ out) {
    const int lane = threadIdx.x & 63;
    const int wave = threadIdx.x >> 6;
    const int l16 = lane & 15, quad = lane >> 4;
    const int rowBase = blockIdx.y * 128 + (wave >> 1) * 64;
    const int colBase = blockIdx.x * 128 + (wave & 1) * 64;

    f32x4 acc[4][4] = {};

#pragma unroll
    for (int k0 = 0; k0 < LAT; k0 += 32) {
        const int kk = k0 + quad * 8;
        bf16x8 ah[4], al[4], bh[4], bl[4];
#pragma unroll
        for (int r = 0; r < 4; ++r) {
            int row = rowBase + r * 16 + l16;
            ah[r] = *(const bf16x8*)(zhi + (size_t)row * LAT + kk);
            al[r] = *(const bf16x8*)(zlo + (size_t)row * LAT + kk);
        }
#pragma unroll
        for (int c = 0; c < 4; ++c) {
            int row = colBase + c * 16 + l16;
            bh[c] = *(const bf16x8*)(zhi + (size_t)row * LAT + kk);
            bl[c] = *(const bf16x8*)(zlo + (size_t)row * LAT + kk);
        }
#pragma unroll
        for (int r = 0; r < 4; ++r)
#pragma unroll
            for (int c = 0; c < 4; ++c) {
                acc[r][c] = __builtin_amdgcn_mfma_f32_16x16x32_bf16(ah[r], bh[c], acc[r][c], 0, 0, 0);
                acc[r][c] = __builtin_amdgcn_mfma_f32_16x16x32_bf16(ah[r], bl[c], acc[r][c], 0, 0, 0);
                acc[r][c] = __builtin_amdgcn_mfma_f32_16x16x32_bf16(al[r], bh[c], acc[r][c], 0, 0, 0);
            }
    }

#pragma unroll
    for (int r = 0; r < 4; ++r)
#pragma unroll
        for (int c = 0; c < 4; ++c)
#pragma unroll
            for (int i = 0; i < 4; ++i) {
                int orow = rowBase + r * 16 + quad * 4 + i;
                int ocol = colBase + c * 16 + l16;
                float t = acc[r][c][i];
                out[(size_t)orow * N_NODES + ocol] = 1.0f / (1.0f + __expf(-t));
            }
}

extern "C" void kernel_launch(void* const* d_in, const int* in_sizes, int n_in,
                              void* d_out, int out_size, void* d_ws, size_t ws_size,
                              hipStream_t stream) {
    const float* x   = (const float*)d_in[0];
    const int*   ei  = (const int*)d_in[1];
    const float* eps = (const float*)d_in[2];
    const float* W1  = (const float*)d_in[3];
    const float* b1  = (const float*)d_in[4];
    const float* Wmu = (const float*)d_in[5];
    const float* bmu = (const float*)d_in[6];
    const float* Wls = (const float*)d_in[7];
    const float* bls = (const float*)d_in[8];
    const int* src = ei;
    const int* dst = ei + NEDGE;

    float* out = (float*)d_out;
    // temporaries parked inside adj region of d_out (zzt overwrites last)
    float* pre1 = out;                    // [8192,256] f32
    float* pre2 = out + 2097152;          // [8192,256] f32; cols 0..127 mu-pre, 128..255 ls-pre
    int*   ibase  = (int*)(out + 4194304);
    int*   cnt    = ibase;                // 8192
    int*   rowptr = ibase + 8192;         // 8193
    int*   cursor = ibase + 16385;        // 8192
    int*   ebuf   = ibase + 24577;        // 262144
    u16* xhi    = (u16*)(out + 4587520);  // [8192,512] bf16 (2097152 float-slots)
    u16* xlo    = (u16*)(out + 6684672);
    u16* h1hi   = (u16*)(out + 8781824);  // [8192,256] bf16 (1048576 float-slots)
    u16* h1lo   = (u16*)(out + 9830400);
    u16* w1thi  = (u16*)(out + 10878976); // [256,512] bf16 (65536 float-slots)
    u16* w1tlo  = (u16*)(out + 11010048);
    u16* wcathi = (u16*)(out + 11141120); // [256,256] bf16: rows 0..127 Wmu^T, 128..255 Wls^T
    u16* wcatlo = (u16*)(out + 11173888);
    float* out_mu = out + 67108864;       // [8192,128]
    float* out_ls = out + 68157440;       // [8192,128]

    float* dinv = (float*)d_ws;                               // 32 KB
    u16* zhi = (u16*)((char*)d_ws + 32768);                   // 2 MB
    u16* zlo = (u16*)((char*)d_ws + 32768 + 2097152);         // 2 MB

    hipMemsetAsync(cnt, 0, 8192 * sizeof(int), stream);

    count_kernel<<<NEDGE / 256, 256, 0, stream>>>(dst, cnt);
    dinv_kernel<<<N_NODES / 256, 256, 0, stream>>>(cnt, dinv);
    scan_kernel<<<1, 256, 0, stream>>>(cnt, rowptr, cursor);
    fill_kernel<<<NEDGE / 256, 256, 0, stream>>>(src, dst, cursor, ebuf);

    // split-bf16 conversions
    convx_kernel<<<4096, 256, 0, stream>>>(x, xhi, xlo);
    convw_kernel<<<(IN_DIM * HID) / 256, 256, 0, stream>>>(W1, w1thi, w1tlo, IN_DIM, HID, IN_DIM, 0);
    convw_kernel<<<(HID * LAT) / 256, 256, 0, stream>>>(Wmu, wcathi, wcatlo, HID, LAT, HID, 0);
    convw_kernel<<<(HID * LAT) / 256, 256, 0, stream>>>(Wls, wcathi, wcatlo, HID, LAT, HID, LAT);

    // pre1 = x @ W1  (MFMA, [8192,512]x[512,256])
    gemm_mfma<<<dim3(HID / 128, N_NODES / 128), 256, 0, stream>>>(xhi, xlo, w1thi, w1tlo,
                                                                  pre1, IN_DIM, HID);
    gather1_kernel<<<N_NODES / 4, 256, 0, stream>>>(pre1, h1hi, h1lo, rowptr, ebuf, dinv, b1);

    // pre2 = h1 @ [Wmu | Wls]  (MFMA, [8192,256]x[256,256])
    gemm_mfma<<<dim3(HID / 128, N_NODES / 128), 256, 0, stream>>>(h1hi, h1lo, wcathi, wcatlo,
                                                                  pre2, HID, HID);

    gather2_kernel<<<N_NODES / 4, 256, 0, stream>>>(pre2, rowptr, ebuf, dinv, bmu, bls, eps,
                                                    out_mu, out_ls, zhi, zlo);

    zzt_kernel<<<dim3(64, 64), 256, 0, stream>>>(zhi, zlo, out);
}

// Round 2
// 526.181 us; speedup vs baseline: 1.0354x; 1.0354x over previous
//
#include <hip/hip_runtime.h>

#define N_NODES 8192
#define IN_DIM  512
#define HID     256
#define LAT     128
#define NEDGE   262144

typedef __attribute__((ext_vector_type(8))) short  bf16x8;
typedef __attribute__((ext_vector_type(4))) float  f32x4;
typedef unsigned short u16;
typedef __attribute__((ext_vector_type(4))) unsigned short u16x4;

// ---- bf16 helpers (manual, RNE) ----
static __device__ inline u16 f2bf(float f) {
    unsigned u = __float_as_uint(f);
    unsigned r = (u + 0x7fffu + ((u >> 16) & 1u)) >> 16;
    return (u16)r;
}
static __device__ inline float bf2f(u16 s) {
    return __uint_as_float(((unsigned)s) << 16);
}

// ================= CSR build =================

__global__ __launch_bounds__(256) void count_kernel(const int* __restrict__ dst,
                                                    int* __restrict__ cnt) {
    int e = blockIdx.x * 256 + threadIdx.x;
    atomicAdd(&cnt[dst[e]], 1);
}

__global__ __launch_bounds__(256) void dinv_kernel(const int* __restrict__ cnt,
                                                   float* __restrict__ dinv) {
    int v = blockIdx.x * 256 + threadIdx.x;
    dinv[v] = rsqrtf((float)cnt[v] + 1.0f);   // +1 self-loop
}

// single-block exclusive scan of 8192 counts -> rowptr[8193], cursor copy
__global__ __launch_bounds__(256) void scan_kernel(const int* __restrict__ cnt,
                                                   int* __restrict__ rowptr,
                                                   int* __restrict__ cursor) {
    __shared__ int part[256];
    const int t = threadIdx.x;
    const int base = t * 32;
    int local[32];
    int s = 0;
#pragma unroll
    for (int i = 0; i < 32; ++i) { local[i] = s; s += cnt[base + i]; }
    part[t] = s;
    __syncthreads();
    for (int off = 1; off < 256; off <<= 1) {
        int v = 0;
        if (t >= off) v = part[t - off];
        __syncthreads();
        if (t >= off) part[t] += v;
        __syncthreads();
    }
    int pre = (t == 0) ? 0 : part[t - 1];
#pragma unroll
    for (int i = 0; i < 32; ++i) {
        int r = pre + local[i];
        rowptr[base + i] = r;
        cursor[base + i] = r;
    }
    if (t == 255) rowptr[8192] = part[255];
}

__global__ __launch_bounds__(256) void fill_kernel(const int* __restrict__ src,
                                                   const int* __restrict__ dst,
                                                   int* __restrict__ cursor,
                                                   int* __restrict__ ebuf) {
    int e = blockIdx.x * 256 + threadIdx.x;
    int pos = atomicAdd(&cursor[dst[e]], 1);
    ebuf[pos] = src[e];
}

// ================= split-bf16 conversion =================

// x [N,512] f32 -> xhi/xlo bf16, 4 elems/thread
__global__ __launch_bounds__(256) void convx_kernel(const float* __restrict__ X,
                                                    u16* __restrict__ xh,
                                                    u16* __restrict__ xl) {
    int t = blockIdx.x * 256 + threadIdx.x;
    f32x4 v = *(const f32x4*)(X + (size_t)t * 4);
    u16x4 h, l;
#pragma unroll
    for (int j = 0; j < 4; ++j) {
        h[j] = f2bf(v[j]);
        l[j] = f2bf(v[j] - bf2f(h[j]));
    }
    *(u16x4*)(xh + (size_t)t * 4) = h;
    *(u16x4*)(xl + (size_t)t * 4) = l;
}

// W [K,N] f32 -> Wt hi/lo [roff+N, Kld] bf16 (transposed), 1 elem/thread
__global__ __launch_bounds__(256) void convw_kernel(const float* __restrict__ W,
                                                    u16* __restrict__ th,
                                                    u16* __restrict__ tl,
                                                    int K, int N, int Kld, int roff) {
    int e = blockIdx.x * 256 + threadIdx.x;
    if (e >= K * N) return;
    int k = e / N, n = e - k * N;
    float f = W[e];
    u16 hi = f2bf(f);
    u16 lo = f2bf(f - bf2f(hi));
    size_t o = (size_t)(roff + n) * Kld + k;
    th[o] = hi;
    tl[o] = lo;
}

// ================= split-bf16 MFMA GEMM =================
// C[M,ldc] = (Ah+Al)[M,K] @ (Bth+Btl)^T  where Bt rows are B columns.
// Block = 4 waves (2x2), each wave a 64x64 tile -> 128x128 per block.
// 3-pass split: hi*hi + hi*lo + lo*hi (lo*lo ~ 2^-16, dropped).
__global__ __launch_bounds__(256) void gemm_mfma(const u16* __restrict__ Ah,
                                                 const u16* __restrict__ Al,
                                                 const u16* __restrict__ Bth,
                                                 const u16* __restrict__ Btl,
                                                 float* __restrict__ C,
                                                 int K, int ldc) {
    const int lane = threadIdx.x & 63;
    const int wave = threadIdx.x >> 6;
    const int l16 = lane & 15, quad = lane >> 4;
    const int rowBase = blockIdx.y * 128 + (wave >> 1) * 64;
    const int colBase = blockIdx.x * 128 + (wave & 1) * 64;

    f32x4 acc[4][4] = {};

    for (int k0 = 0; k0 < K; k0 += 32) {
        const int kk = k0 + quad * 8;
        bf16x8 ah[4], al[4], bh[4], bl[4];
#pragma unroll
        for (int r = 0; r < 4; ++r) {
            int row = rowBase + r * 16 + l16;
            ah[r] = *(const bf16x8*)(Ah + (size_t)row * K + kk);
            al[r] = *(const bf16x8*)(Al + (size_t)row * K + kk);
        }
#pragma unroll
        for (int c = 0; c < 4; ++c) {
            int row = colBase + c * 16 + l16;
            bh[c] = *(const bf16x8*)(Bth + (size_t)row * K + kk);
            bl[c] = *(const bf16x8*)(Btl + (size_t)row * K + kk);
        }
#pragma unroll
        for (int r = 0; r < 4; ++r)
#pragma unroll
            for (int c = 0; c < 4; ++c) {
                acc[r][c] = __builtin_amdgcn_mfma_f32_16x16x32_bf16(ah[r], bh[c], acc[r][c], 0, 0, 0);
                acc[r][c] = __builtin_amdgcn_mfma_f32_16x16x32_bf16(ah[r], bl[c], acc[r][c], 0, 0, 0);
                acc[r][c] = __builtin_amdgcn_mfma_f32_16x16x32_bf16(al[r], bh[c], acc[r][c], 0, 0, 0);
            }
    }

#pragma unroll
    for (int r = 0; r < 4; ++r)
#pragma unroll
        for (int c = 0; c < 4; ++c)
#pragma unroll
            for (int i = 0; i < 4; ++i) {
                int orow = rowBase + r * 16 + quad * 4 + i;
                int ocol = colBase + c * 16 + l16;
                C[(size_t)orow * ldc + ocol] = acc[r][c][i];
            }
}

// ================= CSR gather aggregation =================
// conv1: h1[v] = relu( sum_s nrm*pre1[s] + d2*pre1[v] + b1 ), one wave per node
// output split-bf16 (feeds MFMA gemm2)
__global__ __launch_bounds__(256) void gather1_kernel(const float* __restrict__ pre1,
                                                      u16* __restrict__ h1h,
                                                      u16* __restrict__ h1l,
                                                      const int* __restrict__ rowptr,
                                                      const int* __restrict__ ebuf,
                                                      const float* __restrict__ dinv,
                                                      const float* __restrict__ b1) {
    const int wave = threadIdx.x >> 6, lane = threadIdx.x & 63;
    const int v = blockIdx.x * 4 + wave;
    const int c = lane * 4;
    const float dv = dinv[v];
    f32x4 acc = *(const f32x4*)(pre1 + (size_t)v * HID + c);
    acc *= dv * dv;
    int i = rowptr[v], end = rowptr[v + 1];
    for (; i + 1 < end; i += 2) {
        int s0 = ebuf[i], s1 = ebuf[i + 1];
        float n0 = dv * dinv[s0], n1 = dv * dinv[s1];
        f32x4 h0 = *(const f32x4*)(pre1 + (size_t)s0 * HID + c);
        f32x4 h1v = *(const f32x4*)(pre1 + (size_t)s1 * HID + c);
#pragma unroll
        for (int j = 0; j < 4; ++j) acc[j] += n0 * h0[j] + n1 * h1v[j];
    }
    if (i < end) {
        int s0 = ebuf[i];
        float n0 = dv * dinv[s0];
        f32x4 h0 = *(const f32x4*)(pre1 + (size_t)s0 * HID + c);
#pragma unroll
        for (int j = 0; j < 4; ++j) acc[j] += n0 * h0[j];
    }
    f32x4 bb = *(const f32x4*)(b1 + c);
    u16x4 hv, lv;
#pragma unroll
    for (int j = 0; j < 4; ++j) {
        float h = fmaxf(acc[j] + bb[j], 0.0f);
        hv[j] = f2bf(h);
        lv[j] = f2bf(h - bf2f(hv[j]));
    }
    *(u16x4*)(h1h + (size_t)v * HID + c) = hv;
    *(u16x4*)(h1l + (size_t)v * HID + c) = lv;
}

// conv2 + reparametrize: pre2 cols 0..127 = mu-pre, 128..255 = ls-pre.
__global__ __launch_bounds__(256) void gather2_kernel(const float* __restrict__ pre2,
                                                      const int* __restrict__ rowptr,
                                                      const int* __restrict__ ebuf,
                                                      const float* __restrict__ dinv,
                                                      const float* __restrict__ bmu,
                                                      const float* __restrict__ bls,
                                                      const float* __restrict__ eps,
                                                      float* __restrict__ out_mu,
                                                      float* __restrict__ out_ls,
                                                      u16* __restrict__ zhi,
                                                      u16* __restrict__ zlo) {
    const int wave = threadIdx.x >> 6, lane = threadIdx.x & 63;
    const int v = blockIdx.x * 4 + wave;
    const int c = lane * 4;
    const float dv = dinv[v];
    f32x4 acc = *(const f32x4*)(pre2 + (size_t)v * HID + c);
    acc *= dv * dv;
    int i = rowptr[v], end = rowptr[v + 1];
    for (; i + 1 < end; i += 2) {
        int s0 = ebuf[i], s1 = ebuf[i + 1];
        float n0 = dv * dinv[s0], n1 = dv * dinv[s1];
        f32x4 h0 = *(const f32x4*)(pre2 + (size_t)s0 * HID + c);
        f32x4 h1v = *(const f32x4*)(pre2 + (size_t)s1 * HID + c);
#pragma unroll
        for (int j = 0; j < 4; ++j) acc[j] += n0 * h0[j] + n1 * h1v[j];
    }
    if (i < end) {
        int s0 = ebuf[i];
        float n0 = dv * dinv[s0];
        f32x4 h0 = *(const f32x4*)(pre2 + (size_t)s0 * HID + c);
#pragma unroll
        for (int j = 0; j < 4; ++j) acc[j] += n0 * h0[j];
    }
    // bias
    const float* bias = (lane < 32) ? (bmu + c) : (bls + (c - 128));
    f32x4 bb = *(const f32x4*)bias;
#pragma unroll
    for (int j = 0; j < 4; ++j) acc[j] += bb[j];

    // pair mu (lane<32) with ls (lane+32)
    f32x4 other;
#pragma unroll
    for (int j = 0; j < 4; ++j) other[j] = __shfl(acc[j], (lane + 32) & 63, 64);

    if (lane < 32) {
        int idx = v * LAT + c;
        f32x4 ep = *(const f32x4*)(eps + idx);
        __builtin_nontemporal_store(acc, (f32x4*)(out_mu + idx));
        u16x4 hv, lv;
#pragma unroll
        for (int j = 0; j < 4; ++j) {
            float z = ep[j] * __expf(other[j]) + acc[j];
            u16 hi = f2bf(z);
            hv[j] = hi;
            lv[j] = f2bf(z - bf2f(hi));
        }
        *(u16x4*)(zhi + idx) = hv;
        *(u16x4*)(zlo + idx) = lv;
    } else {
        int idx = v * LAT + (c - 128);
        __builtin_nontemporal_store(acc, (f32x4*)(out_ls + idx));
    }
}

// ================= adj = sigmoid(z z^T), symmetric split-bf16 MFMA =================
// Only lower-triangle blocks (by >= bx) are computed; each off-diagonal block
// writes both its tile and the transposed tile (logit is symmetric in i,j).
// All adjacency writes are nontemporal (write-once stream; keep z in L2).
#define NTRI 2080   // 64*65/2
__global__ __launch_bounds__(256) void zzt_kernel(const u16* __restrict__ zhi,
                                                  const u16* __restrict__ zlo,
                                                  float* __restrict__ out) {
    const int lane = threadIdx.x & 63;
    const int wave = threadIdx.x >> 6;
    const int l16 = lane & 15, quad = lane >> 4;

    // XCD-bijective swizzle: 2080 = 8 * 260
    int bid = (blockIdx.x & 7) * 260 + (blockIdx.x >> 3);
    // triangle decode: by >= bx
    int by = (int)((sqrtf(8.0f * (float)bid + 1.0f) - 1.0f) * 0.5f);
    while ((by + 1) * (by + 2) / 2 <= bid) ++by;
    while (by * (by + 1) / 2 > bid) --by;
    const int bx = bid - by * (by + 1) / 2;

    const int rowBase = by * 128 + (wave >> 1) * 64;
    const int colBase = bx * 128 + (wave & 1) * 64;

    f32x4 acc[4][4] = {};

#pragma unroll
    for (int k0 = 0; k0 < LAT; k0 += 32) {
        const int kk = k0 + quad * 8;
        bf16x8 ah[4], al[4], bh[4], bl[4];
#pragma unroll
        for (int r = 0; r < 4; ++r) {
            int row = rowBase + r * 16 + l16;
            ah[r] = *(const bf16x8*)(zhi + (size_t)row * LAT + kk);
            al[r] = *(const bf16x8*)(zlo + (size_t)row * LAT + kk);
        }
#pragma unroll
        for (int c = 0; c < 4; ++c) {
            int row = colBase + c * 16 + l16;
            bh[c] = *(const bf16x8*)(zhi + (size_t)row * LAT + kk);
            bl[c] = *(const bf16x8*)(zlo + (size_t)row * LAT + kk);
        }
#pragma unroll
        for (int r = 0; r < 4; ++r)
#pragma unroll
            for (int c = 0; c < 4; ++c) {
                acc[r][c] = __builtin_amdgcn_mfma_f32_16x16x32_bf16(ah[r], bh[c], acc[r][c], 0, 0, 0);
                acc[r][c] = __builtin_amdgcn_mfma_f32_16x16x32_bf16(ah[r], bl[c], acc[r][c], 0, 0, 0);
                acc[r][c] = __builtin_amdgcn_mfma_f32_16x16x32_bf16(al[r], bh[c], acc[r][c], 0, 0, 0);
            }
    }

    const bool offdiag = (by != bx);
#pragma unroll
    for (int r = 0; r < 4; ++r)
#pragma unroll
        for (int c = 0; c < 4; ++c) {
            f32x4 sig;
#pragma unroll
            for (int i = 0; i < 4; ++i)
                sig[i] = 1.0f / (1.0f + __expf(-acc[r][c][i]));
            // direct tile: element (row = quad*4+i, col = l16) of fragment
#pragma unroll
            for (int i = 0; i < 4; ++i) {
                int orow = rowBase + r * 16 + quad * 4 + i;
                int ocol = colBase + c * 16 + l16;
                __builtin_nontemporal_store(sig[i], out + (size_t)orow * N_NODES + ocol);
            }
            // transposed tile: lane's 4 values are contiguous in the transposed row
            if (offdiag) {
                int trow = colBase + c * 16 + l16;
                int tcol = rowBase + r * 16 + quad * 4;
                __builtin_nontemporal_store(sig, (f32x4*)(out + (size_t)trow * N_NODES + tcol));
            }
        }
}

extern "C" void kernel_launch(void* const* d_in, const int* in_sizes, int n_in,
                              void* d_out, int out_size, void* d_ws, size_t ws_size,
                              hipStream_t stream) {
    const float* x   = (const float*)d_in[0];
    const int*   ei  = (const int*)d_in[1];
    const float* eps = (const float*)d_in[2];
    const float* W1  = (const float*)d_in[3];
    const float* b1  = (const float*)d_in[4];
    const float* Wmu = (const float*)d_in[5];
    const float* bmu = (const float*)d_in[6];
    const float* Wls = (const float*)d_in[7];
    const float* bls = (const float*)d_in[8];
    const int* src = ei;
    const int* dst = ei + NEDGE;

    float* out = (float*)d_out;
    // temporaries parked inside adj region of d_out (zzt overwrites last)
    float* pre1 = out;                    // [8192,256] f32
    float* pre2 = out + 2097152;          // [8192,256] f32; cols 0..127 mu-pre, 128..255 ls-pre
    int*   ibase  = (int*)(out + 4194304);
    int*   cnt    = ibase;                // 8192
    int*   rowptr = ibase + 8192;         // 8193
    int*   cursor = ibase + 16385;        // 8192
    int*   ebuf   = ibase + 24577;        // 262144
    u16* xhi    = (u16*)(out + 4587520);  // [8192,512] bf16 (2097152 float-slots)
    u16* xlo    = (u16*)(out + 6684672);
    u16* h1hi   = (u16*)(out + 8781824);  // [8192,256] bf16 (1048576 float-slots)
    u16* h1lo   = (u16*)(out + 9830400);
    u16* w1thi  = (u16*)(out + 10878976); // [256,512] bf16 (65536 float-slots)
    u16* w1tlo  = (u16*)(out + 11010048);
    u16* wcathi = (u16*)(out + 11141120); // [256,256] bf16: rows 0..127 Wmu^T, 128..255 Wls^T
    u16* wcatlo = (u16*)(out + 11173888);
    float* out_mu = out + 67108864;       // [8192,128]
    float* out_ls = out + 68157440;       // [8192,128]

    float* dinv = (float*)d_ws;                               // 32 KB
    u16* zhi = (u16*)((char*)d_ws + 32768);                   // 2 MB
    u16* zlo = (u16*)((char*)d_ws + 32768 + 2097152);         // 2 MB

    hipMemsetAsync(cnt, 0, 8192 * sizeof(int), stream);

    count_kernel<<<NEDGE / 256, 256, 0, stream>>>(dst, cnt);
    dinv_kernel<<<N_NODES / 256, 256, 0, stream>>>(cnt, dinv);
    scan_kernel<<<1, 256, 0, stream>>>(cnt, rowptr, cursor);
    fill_kernel<<<NEDGE / 256, 256, 0, stream>>>(src, dst, cursor, ebuf);

    // split-bf16 conversions
    convx_kernel<<<4096, 256, 0, stream>>>(x, xhi, xlo);
    convw_kernel<<<(IN_DIM * HID) / 256, 256, 0, stream>>>(W1, w1thi, w1tlo, IN_DIM, HID, IN_DIM, 0);
    convw_kernel<<<(HID * LAT) / 256, 256, 0, stream>>>(Wmu, wcathi, wcatlo, HID, LAT, HID, 0);
    convw_kernel<<<(HID * LAT) / 256, 256, 0, stream>>>(Wls, wcathi, wcatlo, HID, LAT, HID, LAT);

    // pre1 = x @ W1  (MFMA, [8192,512]x[512,256])
    gemm_mfma<<<dim3(HID / 128, N_NODES / 128), 256, 0, stream>>>(xhi, xlo, w1thi, w1tlo,
                                                                  pre1, IN_DIM, HID);
    gather1_kernel<<<N_NODES / 4, 256, 0, stream>>>(pre1, h1hi, h1lo, rowptr, ebuf, dinv, b1);

    // pre2 = h1 @ [Wmu | Wls]  (MFMA, [8192,256]x[256,256])
    gemm_mfma<<<dim3(HID / 128, N_NODES / 128), 256, 0, stream>>>(h1hi, h1lo, wcathi, wcatlo,
                                                                  pre2, HID, HID);

    gather2_kernel<<<N_NODES / 4, 256, 0, stream>>>(pre2, rowptr, ebuf, dinv, bmu, bls, eps,
                                                    out_mu, out_ls, zhi, zlo);

    zzt_kernel<<<NTRI, 256, 0, stream>>>(zhi, zlo, out);
}

// Round 3
// 495.549 us; speedup vs baseline: 1.0994x; 1.0618x over previous
//
#include <hip/hip_runtime.h>

#define N_NODES 8192
#define IN_DIM  512
#define HID     256
#define LAT     128
#define NEDGE   262144

typedef __attribute__((ext_vector_type(8))) short  bf16x8;
typedef __attribute__((ext_vector_type(4))) float  f32x4;
typedef unsigned short u16;
typedef __attribute__((ext_vector_type(4))) unsigned short u16x4;

// ---- bf16 helpers (manual, RNE) ----
static __device__ inline u16 f2bf(float f) {
    unsigned u = __float_as_uint(f);
    unsigned r = (u + 0x7fffu + ((u >> 16) & 1u)) >> 16;
    return (u16)r;
}
static __device__ inline float bf2f(u16 s) {
    return __uint_as_float(((unsigned)s) << 16);
}

// ================= fused prep: count + convx + convw x3 =================
// block ranges: [0,1024) count | [1024,5120) convx | [5120,5632) convw W1
//               [5632,5760) convw Wmu | [5760,5888) convw Wls
#define PREP_BLOCKS 5888

static __device__ inline void convw_body(const float* __restrict__ W,
                                         u16* __restrict__ th,
                                         u16* __restrict__ tl,
                                         int K, int N, int Kld, int roff, int e) {
    if (e >= K * N) return;
    int k = e / N, n = e - k * N;
    float f = W[e];
    u16 hi = f2bf(f);
    u16 lo = f2bf(f - bf2f(hi));
    size_t o = (size_t)(roff + n) * Kld + k;
    th[o] = hi;
    tl[o] = lo;
}

__global__ __launch_bounds__(256) void prep_kernel(const int* __restrict__ dst,
                                                   int* __restrict__ cnt,
                                                   const float* __restrict__ X,
                                                   u16* __restrict__ xh,
                                                   u16* __restrict__ xl,
                                                   const float* __restrict__ W1,
                                                   u16* __restrict__ w1h,
                                                   u16* __restrict__ w1l,
                                                   const float* __restrict__ Wmu,
                                                   const float* __restrict__ Wls,
                                                   u16* __restrict__ wch,
                                                   u16* __restrict__ wcl) {
    const int b = blockIdx.x, t = threadIdx.x;
    if (b < 1024) {
        int e = b * 256 + t;
        atomicAdd(&cnt[dst[e]], 1);
    } else if (b < 5120) {
        int idx = (b - 1024) * 256 + t;
        f32x4 v = *(const f32x4*)(X + (size_t)idx * 4);
        u16x4 h, l;
#pragma unroll
        for (int j = 0; j < 4; ++j) {
            h[j] = f2bf(v[j]);
            l[j] = f2bf(v[j] - bf2f(h[j]));
        }
        *(u16x4*)(xh + (size_t)idx * 4) = h;
        *(u16x4*)(xl + (size_t)idx * 4) = l;
    } else if (b < 5632) {
        convw_body(W1, w1h, w1l, IN_DIM, HID, IN_DIM, 0, (b - 5120) * 256 + t);
    } else if (b < 5760) {
        convw_body(Wmu, wch, wcl, HID, LAT, HID, 0, (b - 5632) * 256 + t);
    } else {
        convw_body(Wls, wch, wcl, HID, LAT, HID, LAT, (b - 5760) * 256 + t);
    }
}

// ================= scan (+dinv fused) =================
__global__ __launch_bounds__(256) void scan_kernel(const int* __restrict__ cnt,
                                                   int* __restrict__ rowptr,
                                                   int* __restrict__ cursor,
                                                   float* __restrict__ dinv) {
    __shared__ int part[256];
    const int t = threadIdx.x;
    const int base = t * 32;
    int local[32];
    int s = 0;
#pragma unroll
    for (int i = 0; i < 32; ++i) {
        int cv = cnt[base + i];
        local[i] = s; s += cv;
        dinv[base + i] = rsqrtf((float)cv + 1.0f);   // +1 self-loop
    }
    part[t] = s;
    __syncthreads();
    for (int off = 1; off < 256; off <<= 1) {
        int v = 0;
        if (t >= off) v = part[t - off];
        __syncthreads();
        if (t >= off) part[t] += v;
        __syncthreads();
    }
    int pre = (t == 0) ? 0 : part[t - 1];
#pragma unroll
    for (int i = 0; i < 32; ++i) {
        int r = pre + local[i];
        rowptr[base + i] = r;
        cursor[base + i] = r;
    }
    if (t == 255) rowptr[8192] = part[255];
}

// ================= split-bf16 MFMA GEMM body =================
static __device__ inline void gemm_body(const u16* __restrict__ Ah,
                                        const u16* __restrict__ Al,
                                        const u16* __restrict__ Bth,
                                        const u16* __restrict__ Btl,
                                        float* __restrict__ C,
                                        int K, int ldc, int bx, int by, int tid) {
    const int lane = tid & 63;
    const int wave = tid >> 6;
    const int l16 = lane & 15, quad = lane >> 4;
    const int rowBase = by * 128 + (wave >> 1) * 64;
    const int colBase = bx * 128 + (wave & 1) * 64;

    f32x4 acc[4][4] = {};

    for (int k0 = 0; k0 < K; k0 += 32) {
        const int kk = k0 + quad * 8;
        bf16x8 ah[4], al[4], bh[4], bl[4];
#pragma unroll
        for (int r = 0; r < 4; ++r) {
            int row = rowBase + r * 16 + l16;
            ah[r] = *(const bf16x8*)(Ah + (size_t)row * K + kk);
            al[r] = *(const bf16x8*)(Al + (size_t)row * K + kk);
        }
#pragma unroll
        for (int c = 0; c < 4; ++c) {
            int row = colBase + c * 16 + l16;
            bh[c] = *(const bf16x8*)(Bth + (size_t)row * K + kk);
            bl[c] = *(const bf16x8*)(Btl + (size_t)row * K + kk);
        }
#pragma unroll
        for (int r = 0; r < 4; ++r)
#pragma unroll
            for (int c = 0; c < 4; ++c) {
                acc[r][c] = __builtin_amdgcn_mfma_f32_16x16x32_bf16(ah[r], bh[c], acc[r][c], 0, 0, 0);
                acc[r][c] = __builtin_amdgcn_mfma_f32_16x16x32_bf16(ah[r], bl[c], acc[r][c], 0, 0, 0);
                acc[r][c] = __builtin_amdgcn_mfma_f32_16x16x32_bf16(al[r], bh[c], acc[r][c], 0, 0, 0);
            }
    }

#pragma unroll
    for (int r = 0; r < 4; ++r)
#pragma unroll
        for (int c = 0; c < 4; ++c)
#pragma unroll
            for (int i = 0; i < 4; ++i) {
                int orow = rowBase + r * 16 + quad * 4 + i;
                int ocol = colBase + c * 16 + l16;
                C[(size_t)orow * ldc + ocol] = acc[r][c][i];
            }
}

// fused: blocks [0,128) gemm1 (pre1 = x@W1), blocks [128,1152) fill (CSR edge scatter)
__global__ __launch_bounds__(256) void fillgemm_kernel(const u16* __restrict__ xh,
                                                       const u16* __restrict__ xl,
                                                       const u16* __restrict__ w1h,
                                                       const u16* __restrict__ w1l,
                                                       float* __restrict__ pre1,
                                                       const int* __restrict__ src,
                                                       const int* __restrict__ dst,
                                                       int* __restrict__ cursor,
                                                       int* __restrict__ ebuf) {
    const int b = blockIdx.x;
    if (b < 128) {
        gemm_body(xh, xl, w1h, w1l, pre1, IN_DIM, HID, b & 1, b >> 1, threadIdx.x);
    } else {
        int e = (b - 128) * 256 + threadIdx.x;
        int pos = atomicAdd(&cursor[dst[e]], 1);
        ebuf[pos] = src[e];
    }
}

// gemm2: pre2 = h1 @ [Wmu | Wls]
__global__ __launch_bounds__(256) void gemm2_kernel(const u16* __restrict__ h1h,
                                                    const u16* __restrict__ h1l,
                                                    const u16* __restrict__ wch,
                                                    const u16* __restrict__ wcl,
                                                    float* __restrict__ pre2) {
    gemm_body(h1h, h1l, wch, wcl, pre2, HID, HID, blockIdx.x & 1, blockIdx.x >> 1, threadIdx.x);
}

// ================= CSR gather aggregation =================
__global__ __launch_bounds__(256) void gather1_kernel(const float* __restrict__ pre1,
                                                      u16* __restrict__ h1h,
                                                      u16* __restrict__ h1l,
                                                      const int* __restrict__ rowptr,
                                                      const int* __restrict__ ebuf,
                                                      const float* __restrict__ dinv,
                                                      const float* __restrict__ b1) {
    const int wave = threadIdx.x >> 6, lane = threadIdx.x & 63;
    const int v = blockIdx.x * 4 + wave;
    const int c = lane * 4;
    const float dv = dinv[v];
    f32x4 acc = *(const f32x4*)(pre1 + (size_t)v * HID + c);
    acc *= dv * dv;
    int i = rowptr[v], end = rowptr[v + 1];
    for (; i + 1 < end; i += 2) {
        int s0 = ebuf[i], s1 = ebuf[i + 1];
        float n0 = dv * dinv[s0], n1 = dv * dinv[s1];
        f32x4 h0 = *(const f32x4*)(pre1 + (size_t)s0 * HID + c);
        f32x4 h1v = *(const f32x4*)(pre1 + (size_t)s1 * HID + c);
#pragma unroll
        for (int j = 0; j < 4; ++j) acc[j] += n0 * h0[j] + n1 * h1v[j];
    }
    if (i < end) {
        int s0 = ebuf[i];
        float n0 = dv * dinv[s0];
        f32x4 h0 = *(const f32x4*)(pre1 + (size_t)s0 * HID + c);
#pragma unroll
        for (int j = 0; j < 4; ++j) acc[j] += n0 * h0[j];
    }
    f32x4 bb = *(const f32x4*)(b1 + c);
    u16x4 hv, lv;
#pragma unroll
    for (int j = 0; j < 4; ++j) {
        float h = fmaxf(acc[j] + bb[j], 0.0f);
        hv[j] = f2bf(h);
        lv[j] = f2bf(h - bf2f(hv[j]));
    }
    *(u16x4*)(h1h + (size_t)v * HID + c) = hv;
    *(u16x4*)(h1l + (size_t)v * HID + c) = lv;
}

__global__ __launch_bounds__(256) void gather2_kernel(const float* __restrict__ pre2,
                                                      const int* __restrict__ rowptr,
                                                      const int* __restrict__ ebuf,
                                                      const float* __restrict__ dinv,
                                                      const float* __restrict__ bmu,
                                                      const float* __restrict__ bls,
                                                      const float* __restrict__ eps,
                                                      float* __restrict__ out_mu,
                                                      float* __restrict__ out_ls,
                                                      u16* __restrict__ zhi,
                                                      u16* __restrict__ zlo) {
    const int wave = threadIdx.x >> 6, lane = threadIdx.x & 63;
    const int v = blockIdx.x * 4 + wave;
    const int c = lane * 4;
    const float dv = dinv[v];
    f32x4 acc = *(const f32x4*)(pre2 + (size_t)v * HID + c);
    acc *= dv * dv;
    int i = rowptr[v], end = rowptr[v + 1];
    for (; i + 1 < end; i += 2) {
        int s0 = ebuf[i], s1 = ebuf[i + 1];
        float n0 = dv * dinv[s0], n1 = dv * dinv[s1];
        f32x4 h0 = *(const f32x4*)(pre2 + (size_t)s0 * HID + c);
        f32x4 h1v = *(const f32x4*)(pre2 + (size_t)s1 * HID + c);
#pragma unroll
        for (int j = 0; j < 4; ++j) acc[j] += n0 * h0[j] + n1 * h1v[j];
    }
    if (i < end) {
        int s0 = ebuf[i];
        float n0 = dv * dinv[s0];
        f32x4 h0 = *(const f32x4*)(pre2 + (size_t)s0 * HID + c);
#pragma unroll
        for (int j = 0; j < 4; ++j) acc[j] += n0 * h0[j];
    }
    const float* bias = (lane < 32) ? (bmu + c) : (bls + (c - 128));
    f32x4 bb = *(const f32x4*)bias;
#pragma unroll
    for (int j = 0; j < 4; ++j) acc[j] += bb[j];

    f32x4 other;
#pragma unroll
    for (int j = 0; j < 4; ++j) other[j] = __shfl(acc[j], (lane + 32) & 63, 64);

    if (lane < 32) {
        int idx = v * LAT + c;
        f32x4 ep = *(const f32x4*)(eps + idx);
        __builtin_nontemporal_store(acc, (f32x4*)(out_mu + idx));
        u16x4 hv, lv;
#pragma unroll
        for (int j = 0; j < 4; ++j) {
            float z = ep[j] * __expf(other[j]) + acc[j];
            u16 hi = f2bf(z);
            hv[j] = hi;
            lv[j] = f2bf(z - bf2f(hi));
        }
        *(u16x4*)(zhi + idx) = hv;
        *(u16x4*)(zlo + idx) = lv;
    } else {
        int idx = v * LAT + (c - 128);
        __builtin_nontemporal_store(acc, (f32x4*)(out_ls + idx));
    }
}

// ================= adj = sigmoid(z z^T), symmetric, LDS-staged wide stores =================
#define NTRI 2080   // 64*65/2
__global__ __launch_bounds__(256) void zzt_kernel(const u16* __restrict__ zhi,
                                                  const u16* __restrict__ zlo,
                                                  float* __restrict__ out) {
    __shared__ float lds[4][16][68];
    const int lane = threadIdx.x & 63;
    const int wave = threadIdx.x >> 6;
    const int l16 = lane & 15, quad = lane >> 4;

    // XCD-bijective swizzle: 2080 = 8 * 260
    int bid = (blockIdx.x & 7) * 260 + (blockIdx.x >> 3);
    // triangle decode: by >= bx
    int by = (int)((sqrtf(8.0f * (float)bid + 1.0f) - 1.0f) * 0.5f);
    while ((by + 1) * (by + 2) / 2 <= bid) ++by;
    while (by * (by + 1) / 2 > bid) --by;
    const int bx = bid - by * (by + 1) / 2;

    const int rowBase = by * 128 + (wave >> 1) * 64;
    const int colBase = bx * 128 + (wave & 1) * 64;

    f32x4 acc[4][4] = {};

#pragma unroll
    for (int k0 = 0; k0 < LAT; k0 += 32) {
        const int kk = k0 + quad * 8;
        bf16x8 ah[4], al[4], bh[4], bl[4];
#pragma unroll
        for (int r = 0; r < 4; ++r) {
            int row = rowBase + r * 16 + l16;
            ah[r] = *(const bf16x8*)(zhi + (size_t)row * LAT + kk);
            al[r] = *(const bf16x8*)(zlo + (size_t)row * LAT + kk);
        }
#pragma unroll
        for (int c = 0; c < 4; ++c) {
            int row = colBase + c * 16 + l16;
            bh[c] = *(const bf16x8*)(zhi + (size_t)row * LAT + kk);
            bl[c] = *(const bf16x8*)(zlo + (size_t)row * LAT + kk);
        }
#pragma unroll
        for (int r = 0; r < 4; ++r)
#pragma unroll
            for (int c = 0; c < 4; ++c) {
                acc[r][c] = __builtin_amdgcn_mfma_f32_16x16x32_bf16(ah[r], bh[c], acc[r][c], 0, 0, 0);
                acc[r][c] = __builtin_amdgcn_mfma_f32_16x16x32_bf16(ah[r], bl[c], acc[r][c], 0, 0, 0);
                acc[r][c] = __builtin_amdgcn_mfma_f32_16x16x32_bf16(al[r], bh[c], acc[r][c], 0, 0, 0);
            }
    }

    // sigmoid in place
#pragma unroll
    for (int r = 0; r < 4; ++r)
#pragma unroll
        for (int c = 0; c < 4; ++c)
#pragma unroll
            for (int i = 0; i < 4; ++i)
                acc[r][c][i] = 1.0f / (1.0f + __expf(-acc[r][c][i]));

    // direct tiles: per r-group, stage 16x64 in LDS, store 256B-chunk rows
#pragma unroll
    for (int r = 0; r < 4; ++r) {
#pragma unroll
        for (int c = 0; c < 4; ++c)
#pragma unroll
            for (int i = 0; i < 4; ++i)
                lds[wave][quad * 4 + i][c * 16 + l16] = acc[r][c][i];
#pragma unroll
        for (int it = 0; it < 4; ++it) {
            f32x4 v = *(const f32x4*)&lds[wave][it * 4 + quad][l16 * 4];
            int orow = rowBase + r * 16 + it * 4 + quad;
            __builtin_nontemporal_store(v, (f32x4*)(out + (size_t)orow * N_NODES + colBase + l16 * 4));
        }
    }

    // transposed tiles (off-diagonal blocks): per c-group, stage T 16x64, wide stores
    if (by != bx) {
#pragma unroll
        for (int c = 0; c < 4; ++c) {
#pragma unroll
            for (int r = 0; r < 4; ++r) {
                f32x4 tv = acc[r][c];
                *(f32x4*)&lds[wave][l16][r * 16 + quad * 4] = tv;
            }
#pragma unroll
            for (int it = 0; it < 4; ++it) {
                f32x4 v = *(const f32x4*)&lds[wave][it * 4 + quad][l16 * 4];
                int orow = colBase + c * 16 + it * 4 + quad;
                __builtin_nontemporal_store(v, (f32x4*)(out + (size_t)orow * N_NODES + rowBase + l16 * 4));
            }
        }
    }
}

extern "C" void kernel_launch(void* const* d_in, const int* in_sizes, int n_in,
                              void* d_out, int out_size, void* d_ws, size_t ws_size,
                              hipStream_t stream) {
    const float* x   = (const float*)d_in[0];
    const int*   ei  = (const int*)d_in[1];
    const float* eps = (const float*)d_in[2];
    const float* W1  = (const float*)d_in[3];
    const float* b1  = (const float*)d_in[4];
    const float* Wmu = (const float*)d_in[5];
    const float* bmu = (const float*)d_in[6];
    const float* Wls = (const float*)d_in[7];
    const float* bls = (const float*)d_in[8];
    const int* src = ei;
    const int* dst = ei + NEDGE;

    float* out = (float*)d_out;
    // temporaries parked inside adj region of d_out (zzt overwrites last)
    float* pre1 = out;                    // [8192,256] f32
    float* pre2 = out + 2097152;          // [8192,256] f32; cols 0..127 mu-pre, 128..255 ls-pre
    int*   ibase  = (int*)(out + 4194304);
    int*   cnt    = ibase;                // 8192
    int*   rowptr = ibase + 8192;         // 8193
    int*   cursor = ibase + 16385;        // 8192
    int*   ebuf   = ibase + 24577;        // 262144
    u16* xhi    = (u16*)(out + 4587520);  // [8192,512] bf16 (2097152 float-slots)
    u16* xlo    = (u16*)(out + 6684672);
    u16* h1hi   = (u16*)(out + 8781824);  // [8192,256] bf16 (1048576 float-slots)
    u16* h1lo   = (u16*)(out + 9830400);
    u16* w1thi  = (u16*)(out + 10878976); // [256,512] bf16 (65536 float-slots)
    u16* w1tlo  = (u16*)(out + 11010048);
    u16* wcathi = (u16*)(out + 11141120); // [256,256] bf16: rows 0..127 Wmu^T, 128..255 Wls^T
    u16* wcatlo = (u16*)(out + 11173888);
    float* out_mu = out + 67108864;       // [8192,128]
    float* out_ls = out + 68157440;       // [8192,128]

    float* dinv = (float*)d_ws;                               // 32 KB
    u16* zhi = (u16*)((char*)d_ws + 32768);                   // 2 MB
    u16* zlo = (u16*)((char*)d_ws + 32768 + 2097152);         // 2 MB

    hipMemsetAsync(cnt, 0, 8192 * sizeof(int), stream);

    // fused: count + convx + convw(W1) + convw(Wmu) + convw(Wls)
    prep_kernel<<<PREP_BLOCKS, 256, 0, stream>>>(dst, cnt, x, xhi, xlo,
                                                 W1, w1thi, w1tlo, Wmu, Wls, wcathi, wcatlo);

    // scan + dinv
    scan_kernel<<<1, 256, 0, stream>>>(cnt, rowptr, cursor, dinv);

    // fused: gemm1 (pre1 = x@W1) + CSR fill
    fillgemm_kernel<<<128 + 1024, 256, 0, stream>>>(xhi, xlo, w1thi, w1tlo, pre1,
                                                    src, dst, cursor, ebuf);

    gather1_kernel<<<N_NODES / 4, 256, 0, stream>>>(pre1, h1hi, h1lo, rowptr, ebuf, dinv, b1);

    gemm2_kernel<<<128, 256, 0, stream>>>(h1hi, h1lo, wcathi, wcatlo, pre2);

    gather2_kernel<<<N_NODES / 4, 256, 0, stream>>>(pre2, rowptr, ebuf, dinv, bmu, bls, eps,
                                                    out_mu, out_ls, zhi, zlo);

    zzt_kernel<<<NTRI, 256, 0, stream>>>(zhi, zlo, out);
}

// Round 5
// 475.355 us; speedup vs baseline: 1.1461x; 1.0425x over previous
//
#include <hip/hip_runtime.h>

#define N_NODES 8192
#define IN_DIM  512
#define HID     256
#define LAT     128
#define NEDGE   262144

typedef __attribute__((ext_vector_type(8)))  short  bf16x8;
typedef __attribute__((ext_vector_type(4)))  float  f32x4;
typedef __attribute__((ext_vector_type(16))) float  f32x16;
typedef unsigned short u16;
typedef __attribute__((ext_vector_type(4))) unsigned short u16x4;

// ---- bf16 helpers (manual, RNE) ----
static __device__ inline u16 f2bf(float f) {
    unsigned u = __float_as_uint(f);
    unsigned r = (u + 0x7fffu + ((u >> 16) & 1u)) >> 16;
    return (u16)r;
}
static __device__ inline float bf2f(u16 s) {
    return __uint_as_float(((unsigned)s) << 16);
}

// ================= fused prep: count + convx + convw x3 =================
// block ranges: [0,1024) count | [1024,5120) convx | [5120,5632) convw W1
//               [5632,5760) convw Wmu | [5760,5888) convw Wls
#define PREP_BLOCKS 5888

static __device__ inline void convw_body(const float* __restrict__ W,
                                         u16* __restrict__ th,
                                         u16* __restrict__ tl,
                                         int K, int N, int Kld, int roff, int e) {
    if (e >= K * N) return;
    int k = e / N, n = e - k * N;
    float f = W[e];
    u16 hi = f2bf(f);
    u16 lo = f2bf(f - bf2f(hi));
    size_t o = (size_t)(roff + n) * Kld + k;
    th[o] = hi;
    tl[o] = lo;
}

__global__ __launch_bounds__(256) void prep_kernel(const int* __restrict__ dst,
                                                   int* __restrict__ cnt,
                                                   const float* __restrict__ X,
                                                   u16* __restrict__ xh,
                                                   u16* __restrict__ xl,
                                                   const float* __restrict__ W1,
                                                   u16* __restrict__ w1h,
                                                   u16* __restrict__ w1l,
                                                   const float* __restrict__ Wmu,
                                                   const float* __restrict__ Wls,
                                                   u16* __restrict__ wch,
                                                   u16* __restrict__ wcl) {
    const int b = blockIdx.x, t = threadIdx.x;
    if (b < 1024) {
        int e = b * 256 + t;
        atomicAdd(&cnt[dst[e]], 1);
    } else if (b < 5120) {
        int idx = (b - 1024) * 256 + t;
        f32x4 v = *(const f32x4*)(X + (size_t)idx * 4);
        u16x4 h, l;
#pragma unroll
        for (int j = 0; j < 4; ++j) {
            h[j] = f2bf(v[j]);
            l[j] = f2bf(v[j] - bf2f(h[j]));
        }
        *(u16x4*)(xh + (size_t)idx * 4) = h;
        *(u16x4*)(xl + (size_t)idx * 4) = l;
    } else if (b < 5632) {
        convw_body(W1, w1h, w1l, IN_DIM, HID, IN_DIM, 0, (b - 5120) * 256 + t);
    } else if (b < 5760) {
        convw_body(Wmu, wch, wcl, HID, LAT, HID, 0, (b - 5632) * 256 + t);
    } else {
        convw_body(Wls, wch, wcl, HID, LAT, HID, LAT, (b - 5760) * 256 + t);
    }
}

// ================= scan (+dinv fused) =================
__global__ __launch_bounds__(256) void scan_kernel(const int* __restrict__ cnt,
                                                   int* __restrict__ rowptr,
                                                   int* __restrict__ cursor,
                                                   float* __restrict__ dinv) {
    __shared__ int part[256];
    const int t = threadIdx.x;
    const int base = t * 32;
    int local[32];
    int s = 0;
#pragma unroll
    for (int i = 0; i < 32; ++i) {
        int cv = cnt[base + i];
        local[i] = s; s += cv;
        dinv[base + i] = rsqrtf((float)cv + 1.0f);   // +1 self-loop
    }
    part[t] = s;
    __syncthreads();
    for (int off = 1; off < 256; off <<= 1) {
        int v = 0;
        if (t >= off) v = part[t - off];
        __syncthreads();
        if (t >= off) part[t] += v;
        __syncthreads();
    }
    int pre = (t == 0) ? 0 : part[t - 1];
#pragma unroll
    for (int i = 0; i < 32; ++i) {
        int r = pre + local[i];
        rowptr[base + i] = r;
        cursor[base + i] = r;
    }
    if (t == 255) rowptr[8192] = part[255];
}

// ================= split-bf16 MFMA GEMM body (16x16x32) =================
static __device__ inline void gemm_body(const u16* __restrict__ Ah,
                                        const u16* __restrict__ Al,
                                        const u16* __restrict__ Bth,
                                        const u16* __restrict__ Btl,
                                        float* __restrict__ C,
                                        int K, int ldc, int bx, int by, int tid) {
    const int lane = tid & 63;
    const int wave = tid >> 6;
    const int l16 = lane & 15, quad = lane >> 4;
    const int rowBase = by * 128 + (wave >> 1) * 64;
    const int colBase = bx * 128 + (wave & 1) * 64;

    f32x4 acc[4][4] = {};

    for (int k0 = 0; k0 < K; k0 += 32) {
        const int kk = k0 + quad * 8;
        bf16x8 ah[4], al[4], bh[4], bl[4];
#pragma unroll
        for (int r = 0; r < 4; ++r) {
            int row = rowBase + r * 16 + l16;
            ah[r] = *(const bf16x8*)(Ah + (size_t)row * K + kk);
            al[r] = *(const bf16x8*)(Al + (size_t)row * K + kk);
        }
#pragma unroll
        for (int c = 0; c < 4; ++c) {
            int row = colBase + c * 16 + l16;
            bh[c] = *(const bf16x8*)(Bth + (size_t)row * K + kk);
            bl[c] = *(const bf16x8*)(Btl + (size_t)row * K + kk);
        }
#pragma unroll
        for (int r = 0; r < 4; ++r)
#pragma unroll
            for (int c = 0; c < 4; ++c) {
                acc[r][c] = __builtin_amdgcn_mfma_f32_16x16x32_bf16(ah[r], bh[c], acc[r][c], 0, 0, 0);
                acc[r][c] = __builtin_amdgcn_mfma_f32_16x16x32_bf16(ah[r], bl[c], acc[r][c], 0, 0, 0);
                acc[r][c] = __builtin_amdgcn_mfma_f32_16x16x32_bf16(al[r], bh[c], acc[r][c], 0, 0, 0);
            }
    }

#pragma unroll
    for (int r = 0; r < 4; ++r)
#pragma unroll
        for (int c = 0; c < 4; ++c)
#pragma unroll
            for (int i = 0; i < 4; ++i) {
                int orow = rowBase + r * 16 + quad * 4 + i;
                int ocol = colBase + c * 16 + l16;
                C[(size_t)orow * ldc + ocol] = acc[r][c][i];
            }
}

// fused: blocks [0,128) gemm1 (pre1 = x@W1), blocks [128,1152) fill (CSR edge scatter)
__global__ __launch_bounds__(256) void fillgemm_kernel(const u16* __restrict__ xh,
                                                       const u16* __restrict__ xl,
                                                       const u16* __restrict__ w1h,
                                                       const u16* __restrict__ w1l,
                                                       float* __restrict__ pre1,
                                                       const int* __restrict__ src,
                                                       const int* __restrict__ dst,
                                                       int* __restrict__ cursor,
                                                       int* __restrict__ ebuf) {
    const int b = blockIdx.x;
    if (b < 128) {
        gemm_body(xh, xl, w1h, w1l, pre1, IN_DIM, HID, b & 1, b >> 1, threadIdx.x);
    } else {
        int e = (b - 128) * 256 + threadIdx.x;
        int pos = atomicAdd(&cursor[dst[e]], 1);
        ebuf[pos] = src[e];
    }
}

// gemm2: pre2 = h1 @ [Wmu | Wls]
__global__ __launch_bounds__(256) void gemm2_kernel(const u16* __restrict__ h1h,
                                                    const u16* __restrict__ h1l,
                                                    const u16* __restrict__ wch,
                                                    const u16* __restrict__ wcl,
                                                    float* __restrict__ pre2) {
    gemm_body(h1h, h1l, wch, wcl, pre2, HID, HID, blockIdx.x & 1, blockIdx.x >> 1, threadIdx.x);
}

// ================= CSR gather aggregation (4-edge unrolled for MLP) =================
__global__ __launch_bounds__(256) void gather1_kernel(const float* __restrict__ pre1,
                                                      u16* __restrict__ h1h,
                                                      u16* __restrict__ h1l,
                                                      const int* __restrict__ rowptr,
                                                      const int* __restrict__ ebuf,
                                                      const float* __restrict__ dinv,
                                                      const float* __restrict__ b1) {
    const int wave = threadIdx.x >> 6, lane = threadIdx.x & 63;
    const int v = blockIdx.x * 4 + wave;
    const int c = lane * 4;
    const float dv = dinv[v];
    f32x4 acc = *(const f32x4*)(pre1 + (size_t)v * HID + c);
    acc *= dv * dv;
    int i = rowptr[v], end = rowptr[v + 1];
    for (; i + 3 < end; i += 4) {
        int s0 = ebuf[i], s1 = ebuf[i + 1], s2 = ebuf[i + 2], s3 = ebuf[i + 3];
        float n0 = dv * dinv[s0], n1 = dv * dinv[s1];
        float n2 = dv * dinv[s2], n3 = dv * dinv[s3];
        f32x4 h0 = *(const f32x4*)(pre1 + (size_t)s0 * HID + c);
        f32x4 h1v = *(const f32x4*)(pre1 + (size_t)s1 * HID + c);
        f32x4 h2 = *(const f32x4*)(pre1 + (size_t)s2 * HID + c);
        f32x4 h3 = *(const f32x4*)(pre1 + (size_t)s3 * HID + c);
#pragma unroll
        for (int j = 0; j < 4; ++j)
            acc[j] += (n0 * h0[j] + n1 * h1v[j]) + (n2 * h2[j] + n3 * h3[j]);
    }
    for (; i + 1 < end; i += 2) {
        int s0 = ebuf[i], s1 = ebuf[i + 1];
        float n0 = dv * dinv[s0], n1 = dv * dinv[s1];
        f32x4 h0 = *(const f32x4*)(pre1 + (size_t)s0 * HID + c);
        f32x4 h1v = *(const f32x4*)(pre1 + (size_t)s1 * HID + c);
#pragma unroll
        for (int j = 0; j < 4; ++j) acc[j] += n0 * h0[j] + n1 * h1v[j];
    }
    if (i < end) {
        int s0 = ebuf[i];
        float n0 = dv * dinv[s0];
        f32x4 h0 = *(const f32x4*)(pre1 + (size_t)s0 * HID + c);
#pragma unroll
        for (int j = 0; j < 4; ++j) acc[j] += n0 * h0[j];
    }
    f32x4 bb = *(const f32x4*)(b1 + c);
    u16x4 hv, lv;
#pragma unroll
    for (int j = 0; j < 4; ++j) {
        float h = fmaxf(acc[j] + bb[j], 0.0f);
        hv[j] = f2bf(h);
        lv[j] = f2bf(h - bf2f(hv[j]));
    }
    *(u16x4*)(h1h + (size_t)v * HID + c) = hv;
    *(u16x4*)(h1l + (size_t)v * HID + c) = lv;
}

__global__ __launch_bounds__(256) void gather2_kernel(const float* __restrict__ pre2,
                                                      const int* __restrict__ rowptr,
                                                      const int* __restrict__ ebuf,
                                                      const float* __restrict__ dinv,
                                                      const float* __restrict__ bmu,
                                                      const float* __restrict__ bls,
                                                      const float* __restrict__ eps,
                                                      float* __restrict__ out_mu,
                                                      float* __restrict__ out_ls,
                                                      u16* __restrict__ zhi,
                                                      u16* __restrict__ zlo) {
    const int wave = threadIdx.x >> 6, lane = threadIdx.x & 63;
    const int v = blockIdx.x * 4 + wave;
    const int c = lane * 4;
    const float dv = dinv[v];
    f32x4 acc = *(const f32x4*)(pre2 + (size_t)v * HID + c);
    acc *= dv * dv;
    int i = rowptr[v], end = rowptr[v + 1];
    for (; i + 3 < end; i += 4) {
        int s0 = ebuf[i], s1 = ebuf[i + 1], s2 = ebuf[i + 2], s3 = ebuf[i + 3];
        float n0 = dv * dinv[s0], n1 = dv * dinv[s1];
        float n2 = dv * dinv[s2], n3 = dv * dinv[s3];
        f32x4 h0 = *(const f32x4*)(pre2 + (size_t)s0 * HID + c);
        f32x4 h1v = *(const f32x4*)(pre2 + (size_t)s1 * HID + c);
        f32x4 h2 = *(const f32x4*)(pre2 + (size_t)s2 * HID + c);
        f32x4 h3 = *(const f32x4*)(pre2 + (size_t)s3 * HID + c);
#pragma unroll
        for (int j = 0; j < 4; ++j)
            acc[j] += (n0 * h0[j] + n1 * h1v[j]) + (n2 * h2[j] + n3 * h3[j]);
    }
    for (; i + 1 < end; i += 2) {
        int s0 = ebuf[i], s1 = ebuf[i + 1];
        float n0 = dv * dinv[s0], n1 = dv * dinv[s1];
        f32x4 h0 = *(const f32x4*)(pre2 + (size_t)s0 * HID + c);
        f32x4 h1v = *(const f32x4*)(pre2 + (size_t)s1 * HID + c);
#pragma unroll
        for (int j = 0; j < 4; ++j) acc[j] += n0 * h0[j] + n1 * h1v[j];
    }
    if (i < end) {
        int s0 = ebuf[i];
        float n0 = dv * dinv[s0];
        f32x4 h0 = *(const f32x4*)(pre2 + (size_t)s0 * HID + c);
#pragma unroll
        for (int j = 0; j < 4; ++j) acc[j] += n0 * h0[j];
    }
    const float* bias = (lane < 32) ? (bmu + c) : (bls + (c - 128));
    f32x4 bb = *(const f32x4*)bias;
#pragma unroll
    for (int j = 0; j < 4; ++j) acc[j] += bb[j];

    f32x4 other;
#pragma unroll
    for (int j = 0; j < 4; ++j) other[j] = __shfl(acc[j], (lane + 32) & 63, 64);

    if (lane < 32) {
        int idx = v * LAT + c;
        f32x4 ep = *(const f32x4*)(eps + idx);
        __builtin_nontemporal_store(acc, (f32x4*)(out_mu + idx));
        u16x4 hv, lv;
#pragma unroll
        for (int j = 0; j < 4; ++j) {
            float z = ep[j] * __expf(other[j]) + acc[j];
            u16 hi = f2bf(z);
            hv[j] = hi;
            lv[j] = f2bf(z - bf2f(hi));
        }
        *(u16x4*)(zhi + idx) = hv;
        *(u16x4*)(zlo + idx) = lv;
    } else {
        int idx = v * LAT + (c - 128);
        __builtin_nontemporal_store(acc, (f32x4*)(out_ls + idx));
    }
}

// ================= adj = sigmoid(z z^T): 32x32x16 MFMA, swapped operands =================
// mfma(Y, X): acc lane = output ROW, acc reg -> output COL (row-major-friendly).
// Triangle blocks only; direct + transposed tiles staged through LDS for 256B stores.
#define NTRI 2080   // 64*65/2
__global__ __launch_bounds__(256) void zzt_kernel(const u16* __restrict__ zhi,
                                                  const u16* __restrict__ zlo,
                                                  float* __restrict__ out) {
    __shared__ float lds[4][32][68];
    const int lane = threadIdx.x & 63;
    const int wave = threadIdx.x >> 6;
    const int l16 = lane & 15, quad = lane >> 4;
    const int l32 = lane & 31, half = lane >> 5;

    // XCD-bijective swizzle: 2080 = 8 * 260
    int bid = (blockIdx.x & 7) * 260 + (blockIdx.x >> 3);
    // triangle decode: by >= bx
    int by = (int)((sqrtf(8.0f * (float)bid + 1.0f) - 1.0f) * 0.5f);
    while ((by + 1) * (by + 2) / 2 <= bid) ++by;
    while (by * (by + 1) / 2 > bid) --by;
    const int bx = bid - by * (by + 1) / 2;

    const int rowBase = by * 128 + (wave >> 1) * 64;
    const int colBase = bx * 128 + (wave & 1) * 64;

    f32x16 acc[2][2] = {};

#pragma unroll
    for (int k = 0; k < 8; ++k) {
        const int kk = k * 16 + half * 8;
        bf16x8 xh[2], xl[2], yh[2], yl[2];
#pragma unroll
        for (int r = 0; r < 2; ++r) {
            int row = rowBase + r * 32 + l32;
            xh[r] = *(const bf16x8*)(zhi + (size_t)row * LAT + kk);
            xl[r] = *(const bf16x8*)(zlo + (size_t)row * LAT + kk);
        }
#pragma unroll
        for (int cc = 0; cc < 2; ++cc) {
            int row = colBase + cc * 32 + l32;
            yh[cc] = *(const bf16x8*)(zhi + (size_t)row * LAT + kk);
            yl[cc] = *(const bf16x8*)(zlo + (size_t)row * LAT + kk);
        }
#pragma unroll
        for (int r = 0; r < 2; ++r)
#pragma unroll
            for (int cc = 0; cc < 2; ++cc) {
                // swapped: "A"=Y (cols), "B"=X (rows) -> acc lane = row, reg = col
                acc[r][cc] = __builtin_amdgcn_mfma_f32_32x32x16_bf16(yh[cc], xh[r], acc[r][cc], 0, 0, 0);
                acc[r][cc] = __builtin_amdgcn_mfma_f32_32x32x16_bf16(yh[cc], xl[r], acc[r][cc], 0, 0, 0);
                acc[r][cc] = __builtin_amdgcn_mfma_f32_32x32x16_bf16(yl[cc], xh[r], acc[r][cc], 0, 0, 0);
            }
    }

    // sigmoid in place
#pragma unroll
    for (int r = 0; r < 2; ++r)
#pragma unroll
        for (int cc = 0; cc < 2; ++cc)
#pragma unroll
            for (int i = 0; i < 16; ++i)
                acc[r][cc][i] = 1.0f / (1.0f + __expf(-acc[r][cc][i]));

    // ---- direct tiles: per r-group (32 rows x 64 cols), b128 LDS stage, 256B NT stores
#pragma unroll
    for (int r = 0; r < 2; ++r) {
#pragma unroll
        for (int cc = 0; cc < 2; ++cc)
#pragma unroll
            for (int q = 0; q < 4; ++q) {
                f32x4 v = { acc[r][cc][q * 4 + 0], acc[r][cc][q * 4 + 1],
                            acc[r][cc][q * 4 + 2], acc[r][cc][q * 4 + 3] };
                // reg q*4+t -> col = t + 8*q + 4*half (contiguous 4)
                *(f32x4*)&lds[wave][l32][cc * 32 + q * 8 + half * 4] = v;
            }
#pragma unroll
        for (int it = 0; it < 8; ++it) {
            f32x4 v = *(const f32x4*)&lds[wave][it * 4 + quad][l16 * 4];
            int orow = rowBase + r * 32 + it * 4 + quad;
            __builtin_nontemporal_store(v, (f32x4*)(out + (size_t)orow * N_NODES + colBase + l16 * 4));
        }
    }

    // ---- transposed tiles (off-diagonal blocks): per c-group, scalar stage, 256B NT stores
    if (by != bx) {
#pragma unroll
        for (int cc = 0; cc < 2; ++cc) {
#pragma unroll
            for (int r = 0; r < 2; ++r)
#pragma unroll
                for (int q = 0; q < 4; ++q)
#pragma unroll
                    for (int t = 0; t < 4; ++t)
                        lds[wave][q * 8 + half * 4 + t][r * 32 + l32] = acc[r][cc][q * 4 + t];
#pragma unroll
            for (int it = 0; it < 8; ++it) {
                f32x4 v = *(const f32x4*)&lds[wave][it * 4 + quad][l16 * 4];
                int orow = colBase + cc * 32 + it * 4 + quad;
                __builtin_nontemporal_store(v, (f32x4*)(out + (size_t)orow * N_NODES + rowBase + l16 * 4));
            }
        }
    }
}

extern "C" void kernel_launch(void* const* d_in, const int* in_sizes, int n_in,
                              void* d_out, int out_size, void* d_ws, size_t ws_size,
                              hipStream_t stream) {
    const float* x   = (const float*)d_in[0];
    const int*   ei  = (const int*)d_in[1];
    const float* eps = (const float*)d_in[2];
    const float* W1  = (const float*)d_in[3];
    const float* b1  = (const float*)d_in[4];
    const float* Wmu = (const float*)d_in[5];
    const float* bmu = (const float*)d_in[6];
    const float* Wls = (const float*)d_in[7];
    const float* bls = (const float*)d_in[8];
    const int* src = ei;
    const int* dst = ei + NEDGE;

    float* out = (float*)d_out;
    // temporaries parked inside adj region of d_out (zzt overwrites last)
    float* pre1 = out;                    // [8192,256] f32
    float* pre2 = out + 2097152;          // [8192,256] f32; cols 0..127 mu-pre, 128..255 ls-pre
    int*   ibase  = (int*)(out + 4194304);
    int*   cnt    = ibase;                // 8192
    int*   rowptr = ibase + 8192;         // 8193
    int*   cursor = ibase + 16385;        // 8192
    int*   ebuf   = ibase + 24577;        // 262144
    u16* xhi    = (u16*)(out + 4587520);  // [8192,512] bf16 (2097152 float-slots)
    u16* xlo    = (u16*)(out + 6684672);
    u16* h1hi   = (u16*)(out + 8781824);  // [8192,256] bf16 (1048576 float-slots)
    u16* h1lo   = (u16*)(out + 9830400);
    u16* w1thi  = (u16*)(out + 10878976); // [256,512] bf16 (65536 float-slots)
    u16* w1tlo  = (u16*)(out + 11010048);
    u16* wcathi = (u16*)(out + 11141120); // [256,256] bf16: rows 0..127 Wmu^T, 128..255 Wls^T
    u16* wcatlo = (u16*)(out + 11173888);
    float* out_mu = out + 67108864;       // [8192,128]
    float* out_ls = out + 68157440;       // [8192,128]

    float* dinv = (float*)d_ws;                               // 32 KB
    u16* zhi = (u16*)((char*)d_ws + 32768);                   // 2 MB
    u16* zlo = (u16*)((char*)d_ws + 32768 + 2097152);         // 2 MB

    hipMemsetAsync(cnt, 0, 8192 * sizeof(int), stream);

    // fused: count + convx + convw(W1) + convw(Wmu) + convw(Wls)
    prep_kernel<<<PREP_BLOCKS, 256, 0, stream>>>(dst, cnt, x, xhi, xlo,
                                                 W1, w1thi, w1tlo, Wmu, Wls, wcathi, wcatlo);

    // scan + dinv
    scan_kernel<<<1, 256, 0, stream>>>(cnt, rowptr, cursor, dinv);

    // fused: gemm1 (pre1 = x@W1) + CSR fill
    fillgemm_kernel<<<128 + 1024, 256, 0, stream>>>(xhi, xlo, w1thi, w1tlo, pre1,
                                                    src, dst, cursor, ebuf);

    gather1_kernel<<<N_NODES / 4, 256, 0, stream>>>(pre1, h1hi, h1lo, rowptr, ebuf, dinv, b1);

    gemm2_kernel<<<128, 256, 0, stream>>>(h1hi, h1lo, wcathi, wcatlo, pre2);

    gather2_kernel<<<N_NODES / 4, 256, 0, stream>>>(pre2, rowptr, ebuf, dinv, bmu, bls, eps,
                                                    out_mu, out_ls, zhi, zlo);

    zzt_kernel<<<NTRI, 256, 0, stream>>>(zhi, zlo, out);
}